// Round 1
// 569.808 us; speedup vs baseline: 1.0013x; 1.0013x over previous
//
#include <hip/hip_runtime.h>

// Tanh-RNN: B=8192, T=2048, I=2, H=20, FC(H->1) on last h.
// Round 8: same j-split scheme as R7 (8 lanes/row, 3 j/lane, 8 rows/wave,
// 1024 waves = 1/SIMD; h-allgather entirely in VALU DPP, no LDS/barriers),
// with the DPP mov-tax removed:
//  - update_dpp old operand is TIED to dst. old=0 (R7) forces "v_mov dst,0"
//    before every DPP (~18-24 movs/step). Now: dst IS old (garbage, dead --
//    full masks + bound_ctrl=false => all lanes defined by src). 0 movs.
//  - xor4 stage (2 masked DPPs each) replaced by row_half_mirror = lane^7
//    (ctrl 0x141, 1 instr). {7,1,2} spans the octet; slot order
//    M = {0,7,1,6,2,5,3,4}; weights gathered to match.
//  - tanh writes hg[0..2] directly (no hn copies); chunk loop unrolled x2
//    ping-ponging q/qn (no 16-mov buffer swap).
// Butterfly: 3x mir7 -> 6x quad_perm(xor1) -> 12x quad_perm(xor2) = 21 DPPs.

#define T_STEPS 2048
#define B_ROWS  8192
#define NCHUNK  (T_STEPS / 8)

#define XOR1_CTRL 0xB1   // quad_perm(1,0,3,2): lane^1
#define XOR2_CTRL 0x4E   // quad_perm(2,3,0,1): lane^2
#define MIR7_CTRL 0x141  // row_half_mirror: lane^7 within each 8-lane octet

__device__ __forceinline__ float tanh_fast(float a) {
    // tanh(a) = 1 - 2/(exp(2a)+1); exp(2a)=exp2(a*2*log2e). Saturates correctly.
    float e = __builtin_amdgcn_exp2f(a * 2.8853900817779268f);
    float r = __builtin_amdgcn_rcpf(e + 1.0f);
    return fmaf(-2.0f, r, 1.0f);
}

__device__ __forceinline__ float2 fma2(float2 a, float2 b, float2 c) {
    return make_float2(fmaf(a.x, b.x, c.x), fmaf(a.y, b.y, c.y));
}

// In-place DPP: dst = dpp(src). old == dst's current (dead) value, so the
// tied-def of v_mov_b32_dpp costs no extra mov. Full masks + bound_ctrl=false:
// every lane's result is defined by src for these permutations.
template <int CTRL>
__device__ __forceinline__ void dpp_to(float& dst, float src) {
    dst = __int_as_float(__builtin_amdgcn_update_dpp(
        __float_as_int(dst), __float_as_int(src), CTRL, 0xF, 0xF, false));
}

// Epilogue-only variant (old=0, bound_ctrl=true) -- executed once, mov is fine.
template <int CTRL>
__device__ __forceinline__ float dpp_full(float v) {
    return __int_as_float(__builtin_amdgcn_update_dpp(
        0, __float_as_int(v), CTRL, 0xF, 0xF, true));
}

__global__ __launch_bounds__(64, 1) void rnn_fused(
    const float* __restrict__ x,      // [B, T, 2]
    const float* __restrict__ W_ih,   // [20, 2]
    const float* __restrict__ W_hh,   // [20, 20]
    const float* __restrict__ b_ih,   // [20]
    const float* __restrict__ b_hh,   // [20]
    const float* __restrict__ fc_w,   // [1, 20]
    const float* __restrict__ fc_b,   // [1]
    float* __restrict__ out)          // [8192] out, then [8192*20] h_state
{
    const int lane = threadIdx.x & 63;
    const int g    = lane & 7;        // owns j = 3g..3g+2
    const int r    = lane >> 3;       // row within wave
    const int row  = blockIdx.x * 8 + r;

    // Butterfly slot order: after stages (mir7, xor1, xor2) below, the lane's
    // 24-slot h vector holds triplets of g' = g ^ M[slot/3]:
    const int M[8] = {0, 7, 1, 6, 2, 5, 3, 4};

    float2 W2[3][12];                 // pair p covers slots 2p, 2p+1 of hg[]
    float  wi0[3], wi1[3], bsum[3], fcw[3];
#pragma unroll
    for (int jj = 0; jj < 3; ++jj) {
        const int j = 3 * g + jj;
        const bool v = (j < 20);
#pragma unroll
        for (int p = 0; p < 12; ++p) {
            float wv[2];
#pragma unroll
            for (int h = 0; h < 2; ++h) {
                const int slot = 2 * p + h;
                const int k = 3 * (g ^ M[slot / 3]) + (slot % 3);
                wv[h] = (v && k < 20) ? W_hh[j * 20 + k] : 0.0f;
            }
            W2[jj][p] = make_float2(wv[0], wv[1]);
        }
        wi0[jj]  = v ? W_ih[j * 2 + 0] : 0.0f;
        wi1[jj]  = v ? W_ih[j * 2 + 1] : 0.0f;
        bsum[jj] = v ? (b_ih[j] + b_hh[j]) : 0.0f;
        fcw[jj]  = v ? fc_w[j] : 0.0f;
    }

    float hg[24];                     // gathered h in butterfly slot order
#pragma unroll
    for (int i = 0; i < 24; ++i) hg[i] = 0.0f;

    auto step = [&](float x0, float x1) {
        float2 c0 = make_float2(fmaf(x0, wi0[0], bsum[0]), x1 * wi1[0]);
        float2 c1 = make_float2(fmaf(x0, wi0[1], bsum[1]), x1 * wi1[1]);
        float2 c2 = make_float2(fmaf(x0, wi0[2], bsum[2]), x1 * wi1[2]);
#pragma unroll
        for (int p = 0; p < 12; ++p) {
            const float2 hp = make_float2(hg[2 * p], hg[2 * p + 1]);
            c0 = fma2(hp, W2[0][p], c0);
            c1 = fma2(hp, W2[1][p], c1);
            c2 = fma2(hp, W2[2][p], c2);
        }
        hg[0] = tanh_fast(c0.x + c0.y);
        hg[1] = tanh_fast(c1.x + c1.y);
        hg[2] = tanh_fast(c2.x + c2.y);
        // ---- DPP butterfly allgather: 21 instrs, 0 movs, no LDS ----
        dpp_to<MIR7_CTRL>(hg[3], hg[0]);
        dpp_to<MIR7_CTRL>(hg[4], hg[1]);
        dpp_to<MIR7_CTRL>(hg[5], hg[2]);
#pragma unroll
        for (int i = 0; i < 6; ++i)  dpp_to<XOR1_CTRL>(hg[6 + i], hg[i]);
#pragma unroll
        for (int i = 0; i < 12; ++i) dpp_to<XOR2_CTRL>(hg[12 + i], hg[i]);
    };

    // x: per 8-step chunk, 4 float4 per lane (octet shares the cacheline, L1
    // broadcast); double-buffered one chunk ahead, ping-pong q/qn (no copies).
    const float4* xq = (const float4*)(x + (size_t)row * (T_STEPS * 2));
    float4 q[4], qn[4];
#pragma unroll
    for (int i = 0; i < 4; ++i) q[i] = xq[i];

#pragma unroll 1
    for (int c = 0; c < NCHUNK; c += 2) {
        const int c1 = c + 1;                                  // qn <- chunk c+1
        const int c2 = (c + 2 < NCHUNK) ? (c + 2) : c1;        // q  <- chunk c+2 (clamped dummy)
#pragma unroll
        for (int i = 0; i < 4; ++i) qn[i] = xq[4 * c1 + i];

        step(q[0].x, q[0].y); step(q[0].z, q[0].w);
        step(q[1].x, q[1].y); step(q[1].z, q[1].w);
        step(q[2].x, q[2].y); step(q[2].z, q[2].w);
        step(q[3].x, q[3].y); step(q[3].z, q[3].w);

#pragma unroll
        for (int i = 0; i < 4; ++i) q[i] = xq[4 * c2 + i];

        step(qn[0].x, qn[0].y); step(qn[0].z, qn[0].w);
        step(qn[1].x, qn[1].y); step(qn[1].z, qn[1].w);
        step(qn[2].x, qn[2].y); step(qn[2].z, qn[2].w);
        step(qn[3].x, qn[3].y); step(qn[3].z, qn[3].w);
    }

    // ---- epilogue ----
    // h_state: [1, B, H] flat at offset B_ROWS; lane stores its own 3 j's
    {
        const int j0 = 3 * g;
        float* hs = out + B_ROWS + (size_t)row * 20;
        if (j0 + 0 < 20) hs[j0 + 0] = hg[0];
        if (j0 + 1 < 20) hs[j0 + 1] = hg[1];
        if (j0 + 2 < 20) hs[j0 + 2] = hg[2];
    }
    // FC: per-lane partial over own j's, octet tree-reduce (xor1,xor2,mir7)
    {
        float p = hg[0] * fcw[0];
        p = fmaf(hg[1], fcw[1], p);
        p = fmaf(hg[2], fcw[2], p);
        p += dpp_full<XOR1_CTRL>(p);
        p += dpp_full<XOR2_CTRL>(p);
        p += dpp_full<MIR7_CTRL>(p);
        if (g == 0) out[row] = p + fc_b[0];
    }
}

extern "C" void kernel_launch(void* const* d_in, const int* in_sizes, int n_in,
                              void* d_out, int out_size, void* d_ws, size_t ws_size,
                              hipStream_t stream) {
    const float* x    = (const float*)d_in[0];
    const float* W_ih = (const float*)d_in[1];
    const float* W_hh = (const float*)d_in[2];
    const float* b_ih = (const float*)d_in[3];
    const float* b_hh = (const float*)d_in[4];
    const float* fc_w = (const float*)d_in[5];
    const float* fc_b = (const float*)d_in[6];
    float* out = (float*)d_out;

    // 1024 blocks x 64 threads: 1 wave/block, 8 rows/wave -> 1 wave/SIMD
    rnn_fused<<<1024, 64, 0, stream>>>(x, W_ih, W_hh, b_ih, b_hh, fc_w, fc_b, out);
}